// Round 3
// baseline (333.213 us; speedup 1.0000x reference)
//
#include <hip/hip_runtime.h>
#include <cstdint>
#include <cstddef>

typedef _Float16 half8 __attribute__((ext_vector_type(8)));
typedef float floatx16 __attribute__((ext_vector_type(16)));

// ws (f16 elements) layout:
//   W0T  [128n][64k]    @ 0       rows of W0 16..63 transposed; k 48..63 unwritten/never read
//   W1T  [128n][128k]   @ 8192
//   W2T  [4o][128k]     @ 24576   (row o=3 = zeros)
//   cbias[C][128] fp32  @ f16 offset 25088 (byte 50176) : b0 + emb@W0[0:16]
#define WS_W1T 8192
#define WS_W2T 24576
#define WS_CB  25088

__device__ __forceinline__ uint32_t pk2(float a, float b) {
    union { _Float16 h[2]; uint32_t u; } x;
    x.h[0] = (_Float16)a; x.h[1] = (_Float16)b;
    return x.u;
}

__global__ void vdc_prep_kernel(const float* __restrict__ W0,
                                const float* __restrict__ W1,
                                const float* __restrict__ W2,
                                const float* __restrict__ b0,
                                const float* __restrict__ emb_tab,
                                const int* __restrict__ embed_ids,
                                int C,
                                _Float16* __restrict__ ws) {
    int i = blockIdx.x * 256 + threadIdx.x;
    if (i < 6144) {                                   // W0T: 128 x 48
        int n = i & 127, k = i >> 7;
        ws[n * 64 + k] = (_Float16)W0[(16 + k) * 128 + n];
    } else if (i < 22528) {                           // W1T: 128 x 128
        int j = i - 6144;
        int n = j & 127, k = j >> 7;
        ws[WS_W1T + n * 128 + k] = (_Float16)W1[k * 128 + n];
    } else if (i < 23040) {                           // W2T: 4 x 128 (row 3 zero)
        int j = i - 22528;
        int o = j >> 7, k = j & 127;
        ws[WS_W2T + o * 128 + k] = (o < 3) ? (_Float16)W2[k * 3 + o] : (_Float16)0.0f;
    } else if (i < 23552) {                           // cbias: C x 128 fp32
        int j = i - 23040;
        int cc = j >> 7, jj = j & 127;
        if (cc < C) {
            int id = embed_ids[cc];
            float a = b0[jj];
            #pragma unroll
            for (int e = 0; e < 16; ++e)
                a += emb_tab[(size_t)id * 16 + e] * W0[e * 128 + jj];
            ((float*)(ws + WS_CB))[cc * 128 + jj] = a;
        }
    }
}

// LDS: single 32 KB region, phases: X[128m][64k]f16 (16K) -> H0[128m][128k]f16 (32K)
//      -> H1[128m][128k]f16 (32K). Row r, 16B granule g stored at r*stride + ((g^(r&7))*16).
__global__ __launch_bounds__(512, 4) void vdc_mlp_kernel(
    const float* __restrict__ feats,      // [N,32]
    const float* __restrict__ dirs,       // [C,N,3]
    const float* __restrict__ b1,         // [128]
    const float* __restrict__ b2,         // [3]
    const int* __restrict__ sh_deg_p,     // [1]
    const _Float16* __restrict__ ws,      // prepped weights
    float* __restrict__ out,              // [C,N,3]
    int N)
{
    __shared__ uint4 ldsbuf[2048];        // 32 KB
    char* lds = (char*)ldsbuf;

    const int tid  = threadIdx.x;
    const int c    = blockIdx.y;
    const int n0   = blockIdx.x * 128;
    const int lane = tid & 63;
    const int w    = tid >> 6;            // 0..7
    const int ln   = lane & 31;
    const int hl   = lane >> 5;           // k-half selector within frag
    const int mb   = (w & 3) * 32;        // this wave's m-tile
    const int np   = w >> 2;              // this wave's n-half
    const int nb0  = np * 64, nb1 = np * 64 + 32;

    // ---- stage X: feats rows -> granules 0..3 ----
    {
        int e = tid >> 2, q = tid & 3;
        int n = n0 + e; if (n >= N) n = N - 1;
        const float4* fp = (const float4*)(feats + (size_t)n * 32);
        float4 fa = fp[q * 2 + 0];
        float4 fb = fp[q * 2 + 1];
        uint4 u;
        u.x = pk2(fa.x, fa.y); u.y = pk2(fa.z, fa.w);
        u.z = pk2(fb.x, fb.y); u.w = pk2(fb.z, fb.w);
        *(uint4*)(lds + e * 128 + ((q ^ (e & 7)) * 16)) = u;
    }

    // ---- stage X: SH basis -> granules 4..5 ----
    if (tid < 128) {
        int e = tid;
        int n = n0 + e; if (n >= N) n = N - 1;
        const float* dp = dirs + ((size_t)c * N + n) * 3;
        float dx = dp[0], dy = dp[1], dz = dp[2];
        float nrm = sqrtf(dx * dx + dy * dy + dz * dz);
        float inv = 1.0f / fmaxf(nrm, 1e-12f);
        float x = dx * inv, y = dy * inv, z = dz * inv;

        float z2     = z * z;
        float fTmp0B = -1.092548430592079f * z;
        float fC1    = x * x - y * y;
        float fS1    = 2.0f * x * y;
        float fTmp0C = -2.285228997322329f * z2 + 0.4570457994644658f;
        float fTmp1B = 1.445305721320277f * z;
        float fC2    = x * fC1 - y * fS1;
        float fS2    = x * fS1 + y * fC1;

        float sh[16];
        sh[0]  = 0.2820947917738781f;
        sh[1]  = -0.48860251190292f * y;
        sh[2]  = 0.48860251190292f * z;
        sh[3]  = -0.48860251190292f * x;
        sh[4]  = 0.5462742152960395f * fS1;
        sh[5]  = fTmp0B * y;
        sh[6]  = 0.9461746957575601f * z2 - 0.3153915652525201f;
        sh[7]  = fTmp0B * x;
        sh[8]  = 0.5462742152960395f * fC1;
        sh[9]  = -0.5900435899266435f * fS2;
        sh[10] = fTmp1B * fS1;
        sh[11] = fTmp0C * y;
        sh[12] = z * (1.865881662950577f * z2 - 1.119528997770346f);
        sh[13] = fTmp0C * x;
        sh[14] = fTmp1B * fC1;
        sh[15] = -0.5900435899266435f * fC2;

        int deg = sh_deg_p[0];
        int nb  = (deg + 1) * (deg + 1);
        #pragma unroll
        for (int i = 0; i < 16; ++i) if (i >= nb) sh[i] = 0.0f;

        uint4 u0, u1;
        u0.x = pk2(sh[0], sh[1]);   u0.y = pk2(sh[2], sh[3]);
        u0.z = pk2(sh[4], sh[5]);   u0.w = pk2(sh[6], sh[7]);
        u1.x = pk2(sh[8], sh[9]);   u1.y = pk2(sh[10], sh[11]);
        u1.z = pk2(sh[12], sh[13]); u1.w = pk2(sh[14], sh[15]);
        *(uint4*)(lds + e * 128 + ((4 ^ (e & 7)) * 16)) = u0;
        *(uint4*)(lds + e * 128 + ((5 ^ (e & 7)) * 16)) = u1;
    }

    // per-lane biases (global scalar, L1-hot)
    const float* cbp = (const float*)(ws + WS_CB) + c * 128;
    float cb0 = cbp[nb0 + ln];
    float cb1 = cbp[nb1 + ln];
    float bb0 = b1[nb0 + ln];
    float bb1 = b1[nb1 + ln];

    __syncthreads();

    // ---- layer 0: X[128,48] @ W0f -> acc (K = 48, ks chunks of 16) ----
    floatx16 a0j0, a0j1;
    #pragma unroll
    for (int r = 0; r < 16; ++r) { a0j0[r] = 0.0f; a0j1[r] = 0.0f; }
    #pragma unroll
    for (int ks = 0; ks < 3; ++ks) {
        half8 av  = *(const half8*)(lds + (mb + ln) * 128 + (((ks * 2 + hl) ^ (ln & 7)) * 16));
        half8 bv0 = *(const half8*)(ws + (nb0 + ln) * 64 + ks * 16 + hl * 8);
        half8 bv1 = *(const half8*)(ws + (nb1 + ln) * 64 + ks * 16 + hl * 8);
        a0j0 = __builtin_amdgcn_mfma_f32_32x32x16_f16(av, bv0, a0j0, 0, 0, 0);
        a0j1 = __builtin_amdgcn_mfma_f32_32x32x16_f16(av, bv1, a0j1, 0, 0, 0);
    }

    __syncthreads();   // all X reads done before H0 overwrites

    // ---- layer0 epilogue: +cbias, relu, f16 -> H0[m][k] (transposed C->A layout) ----
    #pragma unroll
    for (int j = 0; j < 2; ++j) {
        int k1  = (j ? nb1 : nb0) + ln;
        int g   = k1 >> 3;
        int off = (k1 & 7) * 2;
        float cb = j ? cb1 : cb0;
        #pragma unroll
        for (int r = 0; r < 16; ++r) {
            int m = mb + (r & 3) + 8 * (r >> 2) + 4 * hl;
            float v = fmaxf((j ? a0j1[r] : a0j0[r]) + cb, 0.0f);
            *(_Float16*)(lds + m * 256 + ((g ^ (m & 7)) * 16) + off) = (_Float16)v;
        }
    }

    __syncthreads();

    // ---- layer 1: H0[128,128] @ W1 ----
    floatx16 a1j0, a1j1;
    #pragma unroll
    for (int r = 0; r < 16; ++r) { a1j0[r] = 0.0f; a1j1[r] = 0.0f; }
    #pragma unroll
    for (int ks = 0; ks < 8; ++ks) {
        half8 av  = *(const half8*)(lds + (mb + ln) * 256 + (((ks * 2 + hl) ^ (ln & 7)) * 16));
        half8 bv0 = *(const half8*)(ws + WS_W1T + (nb0 + ln) * 128 + ks * 16 + hl * 8);
        half8 bv1 = *(const half8*)(ws + WS_W1T + (nb1 + ln) * 128 + ks * 16 + hl * 8);
        a1j0 = __builtin_amdgcn_mfma_f32_32x32x16_f16(av, bv0, a1j0, 0, 0, 0);
        a1j1 = __builtin_amdgcn_mfma_f32_32x32x16_f16(av, bv1, a1j1, 0, 0, 0);
    }

    __syncthreads();   // all H0 reads done before H1 overwrites

    // ---- layer1 epilogue: +b1, relu, f16 -> H1[m][k] ----
    #pragma unroll
    for (int j = 0; j < 2; ++j) {
        int k1  = (j ? nb1 : nb0) + ln;
        int g   = k1 >> 3;
        int off = (k1 & 7) * 2;
        float bb = j ? bb1 : bb0;
        #pragma unroll
        for (int r = 0; r < 16; ++r) {
            int m = mb + (r & 3) + 8 * (r >> 2) + 4 * hl;
            float v = fmaxf((j ? a1j1[r] : a1j0[r]) + bb, 0.0f);
            *(_Float16*)(lds + m * 256 + ((g ^ (m & 7)) * 16) + off) = (_Float16)v;
        }
    }

    __syncthreads();

    // ---- layer 2: H1[128,128] @ W2T (cols >=3 are garbage, never stored) ----
    if (np == 0) {
        floatx16 a2;
        #pragma unroll
        for (int r = 0; r < 16; ++r) a2[r] = 0.0f;
        #pragma unroll
        for (int ks = 0; ks < 8; ++ks) {
            half8 av = *(const half8*)(lds + (mb + ln) * 256 + (((ks * 2 + hl) ^ (ln & 7)) * 16));
            half8 bw = *(const half8*)(ws + WS_W2T + (ln & 3) * 128 + ks * 16 + hl * 8);
            a2 = __builtin_amdgcn_mfma_f32_32x32x16_f16(av, bw, a2, 0, 0, 0);
        }
        if (ln < 3) {
            float bo = b2[ln];
            #pragma unroll
            for (int r = 0; r < 16; ++r) {
                int m = mb + (r & 3) + 8 * (r >> 2) + 4 * hl;
                int n = n0 + m;
                if (n < N)
                    out[((size_t)c * N + n) * 3 + ln] = a2[r] + bo;
            }
        }
    }
}

extern "C" void kernel_launch(void* const* d_in, const int* in_sizes, int n_in,
                              void* d_out, int out_size, void* d_ws, size_t ws_size,
                              hipStream_t stream) {
    const float* feats   = (const float*)d_in[0];
    const float* dirs    = (const float*)d_in[1];
    const float* emb_tab = (const float*)d_in[2];
    const float* W0      = (const float*)d_in[3];
    const float* b0      = (const float*)d_in[4];
    const float* W1      = (const float*)d_in[5];
    const float* b1      = (const float*)d_in[6];
    const float* W2      = (const float*)d_in[7];
    const float* b2      = (const float*)d_in[8];
    const int*   eids    = (const int*)d_in[9];
    const int*   shd     = (const int*)d_in[10];
    float* outp          = (float*)d_out;

    int N = in_sizes[0] / 32;    // features [N,32]
    int C = in_sizes[9];         // embed_ids [C]

    _Float16* wsh = (_Float16*)d_ws;    // ~52 KB used

    vdc_prep_kernel<<<92, 256, 0, stream>>>(W0, W1, W2, b0, emb_tab, eids, C, wsh);

    dim3 grid((N + 127) / 128, C);
    vdc_mlp_kernel<<<grid, 512, 0, stream>>>(
        feats, dirs, b1, b2, shd, wsh, outp, N);
}

// Round 5
// 249.403 us; speedup vs baseline: 1.3360x; 1.3360x over previous
//
#include <hip/hip_runtime.h>
#include <cstdint>
#include <cstddef>

typedef _Float16 half8 __attribute__((ext_vector_type(8)));
typedef __fp16 fp16x2 __attribute__((ext_vector_type(2)));
typedef float floatx16 __attribute__((ext_vector_type(16)));

// ws (f16 elements) layout (C = #cameras, runtime):
//   W0Tc [C][128 j][64 k] @ 0        k<48: W0[(16+k)*128+j]; k==48: cbias(c,j)=b0[j]+emb_c.W0[0:16,j]; else 0
//   W1T  [128 j'][144 k]  @ C*8192   k<128: W1[k*128+j'];  k==128: b1[j'];  else 0
//   W2T  [32 o][144 k]    @ C*8192+18432   o<3: k<128: W2[k*3+o]; k==128: b2[o]; else 0

__global__ void vdc_prep_kernel(const float* __restrict__ W0,
                                const float* __restrict__ W1,
                                const float* __restrict__ W2,
                                const float* __restrict__ b0,
                                const float* __restrict__ b1,
                                const float* __restrict__ b2,
                                const float* __restrict__ emb_tab,
                                const int* __restrict__ embed_ids,
                                int C,
                                _Float16* __restrict__ ws) {
    int i = blockIdx.x * 256 + threadIdx.x;
    int w0end = C * 8192;
    int w1end = w0end + 18432;
    int w2end = w1end + 4608;
    float v = 0.0f;
    if (i < w0end) {
        int c = i >> 13, r = i & 8191;
        int j = r >> 6, k = r & 63;
        if (k < 48) v = W0[(16 + k) * 128 + j];
        else if (k == 48) {
            int id = embed_ids[c];
            v = b0[j];
            #pragma unroll
            for (int e = 0; e < 16; ++e)
                v += emb_tab[(size_t)id * 16 + e] * W0[e * 128 + j];
        }
        ws[i] = (_Float16)v;
    } else if (i < w1end) {
        int r = i - w0end;
        int j = r / 144, k = r - j * 144;
        if (k < 128) v = W1[k * 128 + j];
        else if (k == 128) v = b1[j];
        ws[i] = (_Float16)v;
    } else if (i < w2end) {
        int r = i - w1end;
        int o = r / 144, k = r - o * 144;
        if (o < 3) {
            if (k < 128) v = W2[k * 3 + o];
            else if (k == 128) v = b2[o];
        }
        ws[i] = (_Float16)v;
    }
}

union U4 { unsigned u[4]; half8 h; };

__device__ __forceinline__ unsigned pkr(float a, float b) {
    union { fp16x2 h; unsigned u; } x;
    x.h = __builtin_amdgcn_cvt_pkrtz(a, b);
    return x.u;
}

// acc tile (C-layout: local row = (r&3)+8*(r>>2)+4*hl, col = ln) -> two B-frag
// half8 chunks (k-order rows 0..15 and 16..31) via relu + pack + lane^32 exchange.
__device__ __forceinline__ void transition(const floatx16& a, int hl,
                                           half8& lo, half8& hi) {
    unsigned p0 = pkr(fmaxf(a[0],  0.f), fmaxf(a[1],  0.f)); // rows (0,1)+4hl
    unsigned p1 = pkr(fmaxf(a[2],  0.f), fmaxf(a[3],  0.f)); // rows (2,3)+4hl
    unsigned p2 = pkr(fmaxf(a[4],  0.f), fmaxf(a[5],  0.f)); // rows (8,9)+4hl
    unsigned p3 = pkr(fmaxf(a[6],  0.f), fmaxf(a[7],  0.f)); // rows (10,11)+4hl
    unsigned p4 = pkr(fmaxf(a[8],  0.f), fmaxf(a[9],  0.f)); // rows (16,17)+4hl
    unsigned p5 = pkr(fmaxf(a[10], 0.f), fmaxf(a[11], 0.f)); // rows (18,19)+4hl
    unsigned p6 = pkr(fmaxf(a[12], 0.f), fmaxf(a[13], 0.f)); // rows (24,25)+4hl
    unsigned p7 = pkr(fmaxf(a[14], 0.f), fmaxf(a[15], 0.f)); // rows (26,27)+4hl
    // hl=0 sends p2,p3,p6,p7 (rows 8-11,24-27); hl=1 sends p0,p1,p4,p5 (rows 4-7,20-23)
    unsigned r0 = __shfl_xor(hl ? p0 : p2, 32);
    unsigned r1 = __shfl_xor(hl ? p1 : p3, 32);
    unsigned r2 = __shfl_xor(hl ? p4 : p6, 32);
    unsigned r3 = __shfl_xor(hl ? p5 : p7, 32);
    U4 L, H;
    L.u[0] = hl ? r0 : p0;   // hl0: rows 0-1   hl1: rows 8-9
    L.u[1] = hl ? r1 : p1;   //      rows 2-3        rows 10-11
    L.u[2] = hl ? p2 : r0;   //      rows 4-5        rows 12-13
    L.u[3] = hl ? p3 : r1;   //      rows 6-7        rows 14-15
    H.u[0] = hl ? r2 : p4;   //      rows 16-17      rows 24-25
    H.u[1] = hl ? r3 : p5;   //      rows 18-19      rows 26-27
    H.u[2] = hl ? p6 : r2;   //      rows 20-21      rows 28-29
    H.u[3] = hl ? p7 : r3;   //      rows 22-23      rows 30-31
    lo = L.h; hi = H.h;
}

#define MFMA(a, b, c) __builtin_amdgcn_mfma_f32_32x32x16_f16((a), (b), (c), 0, 0, 0)

__global__ __launch_bounds__(256, 3) void vdc_mlp_kernel(
    const float* __restrict__ feats,      // [N,32]
    const float* __restrict__ dirs,       // [C,N,3]
    const int* __restrict__ sh_deg_p,     // [1]
    const _Float16* __restrict__ ws,
    float* __restrict__ out,              // [C,N,3]
    int N, int C)
{
    const int tid   = threadIdx.x;
    const int c     = blockIdx.y;
    const int w     = tid >> 6;
    const int lane  = tid & 63;
    const int ln    = lane & 31;
    const int hl    = lane >> 5;
    const int wbase = (blockIdx.x * 4 + w) * 32;
    int n = wbase + ln; if (n >= N) n = N - 1;

    const _Float16* w0p = ws + c * 8192;
    const _Float16* w1p = ws + C * 8192;
    const _Float16* w2p = w1p + 18432;

    // ---- layer0 B-frags: chunks 0,1 = feats; chunk 2 = SH; chunk 3 = bias const ----
    half8 bx0, bx1, bx2, bbias;
    {
        const float* fp = feats + (size_t)n * 32 + hl * 8;
        float4 f0 = *(const float4*)(fp);
        float4 f1 = *(const float4*)(fp + 4);
        float4 f2 = *(const float4*)(fp + 16);
        float4 f3 = *(const float4*)(fp + 20);
        U4 u0, u1;
        u0.u[0] = pkr(f0.x, f0.y); u0.u[1] = pkr(f0.z, f0.w);
        u0.u[2] = pkr(f1.x, f1.y); u0.u[3] = pkr(f1.z, f1.w);
        u1.u[0] = pkr(f2.x, f2.y); u1.u[1] = pkr(f2.z, f2.w);
        u1.u[2] = pkr(f3.x, f3.y); u1.u[3] = pkr(f3.z, f3.w);
        bx0 = u0.h; bx1 = u1.h;
    }
    {
        const float* dp = dirs + ((size_t)c * N + n) * 3;
        float dx = dp[0], dy = dp[1], dz = dp[2];
        float nrm = sqrtf(dx * dx + dy * dy + dz * dz);
        float inv = 1.0f / fmaxf(nrm, 1e-12f);
        float x = dx * inv, y = dy * inv, z = dz * inv;

        float z2     = z * z;
        float fTmp0B = -1.092548430592079f * z;
        float fC1    = x * x - y * y;
        float fS1    = 2.0f * x * y;
        float fTmp0C = -2.285228997322329f * z2 + 0.4570457994644658f;
        float fTmp1B = 1.445305721320277f * z;
        float fC2    = x * fC1 - y * fS1;
        float fS2    = x * fS1 + y * fC1;

        float sh[16];
        sh[0]  = 0.2820947917738781f;
        sh[1]  = -0.48860251190292f * y;
        sh[2]  = 0.48860251190292f * z;
        sh[3]  = -0.48860251190292f * x;
        sh[4]  = 0.5462742152960395f * fS1;
        sh[5]  = fTmp0B * y;
        sh[6]  = 0.9461746957575601f * z2 - 0.3153915652525201f;
        sh[7]  = fTmp0B * x;
        sh[8]  = 0.5462742152960395f * fC1;
        sh[9]  = -0.5900435899266435f * fS2;
        sh[10] = fTmp1B * fS1;
        sh[11] = fTmp0C * y;
        sh[12] = z * (1.865881662950577f * z2 - 1.119528997770346f);
        sh[13] = fTmp0C * x;
        sh[14] = fTmp1B * fC1;
        sh[15] = -0.5900435899266435f * fC2;

        int deg = sh_deg_p[0];
        int nb  = (deg + 1) * (deg + 1);
        #pragma unroll
        for (int i = 0; i < 16; ++i) if (i >= nb) sh[i] = 0.0f;

        float s[8];
        #pragma unroll
        for (int i = 0; i < 8; ++i) s[i] = hl ? sh[8 + i] : sh[i];
        U4 u2;
        u2.u[0] = pkr(s[0], s[1]); u2.u[1] = pkr(s[2], s[3]);
        u2.u[2] = pkr(s[4], s[5]); u2.u[3] = pkr(s[6], s[7]);
        bx2 = u2.h;

        U4 ub;
        ub.u[0] = hl ? 0u : 0x00003C00u;   // f16 1.0 at k-offset 0, hl=0 only
        ub.u[1] = 0u; ub.u[2] = 0u; ub.u[3] = 0u;
        bbias = ub.h;
    }

    // ---- layer 0: H0^T[128 j][32 e] = W0fT @ X^T (+cbias via K-chunk 3) ----
    floatx16 acc[4];
    #pragma unroll
    for (int mt = 0; mt < 4; ++mt)
        #pragma unroll
        for (int r = 0; r < 16; ++r) acc[mt][r] = 0.0f;

    #pragma unroll
    for (int mt = 0; mt < 4; ++mt) {
        const _Float16* ap = w0p + (mt * 32 + ln) * 64 + hl * 8;
        half8 a0 = *(const half8*)(ap);
        half8 a1 = *(const half8*)(ap + 16);
        half8 a2 = *(const half8*)(ap + 32);
        half8 a3 = *(const half8*)(ap + 48);
        acc[mt] = MFMA(a0, bx0, acc[mt]);
        acc[mt] = MFMA(a1, bx1, acc[mt]);
        acc[mt] = MFMA(a2, bx2, acc[mt]);
        acc[mt] = MFMA(a3, bbias, acc[mt]);
    }

    // ---- transition: acc -> layer1 B-frags (k = j, 8 chunks) ----
    half8 hx[8];
    #pragma unroll
    for (int mt = 0; mt < 4; ++mt)
        transition(acc[mt], hl, hx[2 * mt], hx[2 * mt + 1]);

    // ---- layer 1: H1^T = W1T @ H0^T (+b1 via K-chunk 8) ----
    floatx16 acc2[4];
    #pragma unroll
    for (int mt = 0; mt < 4; ++mt)
        #pragma unroll
        for (int r = 0; r < 16; ++r) acc2[mt][r] = 0.0f;

    #pragma unroll
    for (int mt = 0; mt < 4; ++mt) {
        const _Float16* ap = w1p + (mt * 32 + ln) * 144 + hl * 8;
        #pragma unroll
        for (int ks = 0; ks < 8; ++ks) {
            half8 a = *(const half8*)(ap + ks * 16);
            acc2[mt] = MFMA(a, hx[ks], acc2[mt]);
        }
        half8 ab = *(const half8*)(ap + 128);
        acc2[mt] = MFMA(ab, bbias, acc2[mt]);
    }

    // ---- transition 2 ----
    half8 gx[8];
    #pragma unroll
    for (int mt = 0; mt < 4; ++mt)
        transition(acc2[mt], hl, gx[2 * mt], gx[2 * mt + 1]);

    // ---- layer 2: out^T[32 o][32 e] (rows >=3 garbage, never stored) ----
    floatx16 a3;
    #pragma unroll
    for (int r = 0; r < 16; ++r) a3[r] = 0.0f;
    {
        const _Float16* ap = w2p + ln * 144 + hl * 8;
        #pragma unroll
        for (int ks = 0; ks < 8; ++ks) {
            half8 a = *(const half8*)(ap + ks * 16);
            a3 = MFMA(a, gx[ks], a3);
        }
        half8 ab = *(const half8*)(ap + 128);
        a3 = MFMA(ab, bbias, a3);
    }

    // D: col = e = ln, row = (r&3)+8*(r>>2)+4*hl -> hl=0 regs 0,1,2 are o=0,1,2
    if (hl == 0) {
        int nn = wbase + ln;
        if (nn < N) {
            float* op = out + ((size_t)c * N + nn) * 3;
            op[0] = a3[0];
            op[1] = a3[1];
            op[2] = a3[2];
        }
    }
}

extern "C" void kernel_launch(void* const* d_in, const int* in_sizes, int n_in,
                              void* d_out, int out_size, void* d_ws, size_t ws_size,
                              hipStream_t stream) {
    const float* feats   = (const float*)d_in[0];
    const float* dirs    = (const float*)d_in[1];
    const float* emb_tab = (const float*)d_in[2];
    const float* W0      = (const float*)d_in[3];
    const float* b0      = (const float*)d_in[4];
    const float* W1      = (const float*)d_in[5];
    const float* b1      = (const float*)d_in[6];
    const float* W2      = (const float*)d_in[7];
    const float* b2      = (const float*)d_in[8];
    const int*   eids    = (const int*)d_in[9];
    const int*   shd     = (const int*)d_in[10];
    float* outp          = (float*)d_out;

    int N = in_sizes[0] / 32;    // features [N,32]
    int C = in_sizes[9];         // embed_ids [C]

    _Float16* wsh = (_Float16*)d_ws;

    int ws_elems = C * 8192 + 18432 + 4608;
    vdc_prep_kernel<<<(ws_elems + 255) / 256, 256, 0, stream>>>(
        W0, W1, W2, b0, b1, b2, emb_tab, eids, C, wsh);

    int waves_per_cam = (N + 31) / 32;
    dim3 grid((waves_per_cam + 3) / 4, C);
    vdc_mlp_kernel<<<grid, 256, 0, stream>>>(
        feats, dirs, shd, wsh, outp, N, C);
}

// Round 6
// 183.373 us; speedup vs baseline: 1.8171x; 1.3601x over previous
//
#include <hip/hip_runtime.h>
#include <cstdint>
#include <cstddef>

typedef _Float16 half8 __attribute__((ext_vector_type(8)));
typedef __fp16 fp16x2 __attribute__((ext_vector_type(2)));
typedef float floatx16 __attribute__((ext_vector_type(16)));

// ws: frag-linear weight blobs. chunk = 1024 B = 64 lanes x 8 f16, lane l holds
// A[row = tile*32 + (l&31)][k = kchunk*16 + (l>>5)*8 + i], i=0..7.
//   W0c [C][16 chunks]  @ f16 0       (mt 0..3) x (ks 0..3); k<48: W0[(16+k)*128+j],
//                                     k==48: cbias(c,j)=b0[j]+emb_c.W0[0:16,j], else 0
//   W1  [36 chunks]     @ C*8192      (mt 0..3) x (ks 0..8); k<128: W1[k*128+j], k==128: b1[j], else 0
//   W2  [9 chunks]      @ C*8192+18432  (ks 0..8); o=(l&31): o<3 ? (k<128? W2[k*3+o] : k==128? b2[o] : 0) : 0

__global__ void vdc_prep_kernel(const float* __restrict__ W0,
                                const float* __restrict__ W1,
                                const float* __restrict__ W2,
                                const float* __restrict__ b0,
                                const float* __restrict__ b1,
                                const float* __restrict__ b2,
                                const float* __restrict__ emb_tab,
                                const int* __restrict__ embed_ids,
                                int C,
                                _Float16* __restrict__ ws) {
    int i = blockIdx.x * 256 + threadIdx.x;
    int w0end = C * 8192;
    int w1end = w0end + 18432;
    int w2end = w1end + 4608;
    float v = 0.0f;
    if (i < w0end) {
        int c = i >> 13, r = i & 8191;
        int ci = r >> 9, l = (r >> 3) & 63, ii = r & 7;
        int mt = ci >> 2, ks = ci & 3;
        int j  = mt * 32 + (l & 31);
        int kk = ks * 16 + (l >> 5) * 8 + ii;
        if (kk < 48) v = W0[(16 + kk) * 128 + j];
        else if (kk == 48) {
            int id = embed_ids[c];
            v = b0[j];
            #pragma unroll
            for (int e = 0; e < 16; ++e)
                v += emb_tab[(size_t)id * 16 + e] * W0[e * 128 + j];
        }
        ws[i] = (_Float16)v;
    } else if (i < w1end) {
        int r = i - w0end;
        int ci = r >> 9, l = (r >> 3) & 63, ii = r & 7;
        int mt = ci / 9, ks = ci - mt * 9;
        int j  = mt * 32 + (l & 31);
        int kk = ks * 16 + (l >> 5) * 8 + ii;
        if (kk < 128) v = W1[kk * 128 + j];
        else if (kk == 128) v = b1[j];
        ws[i] = (_Float16)v;
    } else if (i < w2end) {
        int r = i - w1end;
        int ks = r >> 9, l = (r >> 3) & 63, ii = r & 7;
        int o  = l & 31;
        int kk = ks * 16 + (l >> 5) * 8 + ii;
        if (o < 3) {
            if (kk < 128) v = W2[kk * 3 + o];
            else if (kk == 128) v = b2[o];
        }
        ws[i] = (_Float16)v;
    }
}

union U4 { unsigned u[4]; half8 h; };

__device__ __forceinline__ unsigned pkr(float a, float b) {
    union { fp16x2 h; unsigned u; } x;
    x.h = __builtin_amdgcn_cvt_pkrtz(a, b);
    return x.u;
}

// acc tile (C-layout) -> two B-frag half8 chunks via relu+pack+lane^32 exchange.
__device__ __forceinline__ void transition(const floatx16& a, int hl,
                                           half8& lo, half8& hi) {
    unsigned p0 = pkr(fmaxf(a[0],  0.f), fmaxf(a[1],  0.f));
    unsigned p1 = pkr(fmaxf(a[2],  0.f), fmaxf(a[3],  0.f));
    unsigned p2 = pkr(fmaxf(a[4],  0.f), fmaxf(a[5],  0.f));
    unsigned p3 = pkr(fmaxf(a[6],  0.f), fmaxf(a[7],  0.f));
    unsigned p4 = pkr(fmaxf(a[8],  0.f), fmaxf(a[9],  0.f));
    unsigned p5 = pkr(fmaxf(a[10], 0.f), fmaxf(a[11], 0.f));
    unsigned p6 = pkr(fmaxf(a[12], 0.f), fmaxf(a[13], 0.f));
    unsigned p7 = pkr(fmaxf(a[14], 0.f), fmaxf(a[15], 0.f));
    unsigned r0 = __shfl_xor(hl ? p0 : p2, 32);
    unsigned r1 = __shfl_xor(hl ? p1 : p3, 32);
    unsigned r2 = __shfl_xor(hl ? p4 : p6, 32);
    unsigned r3 = __shfl_xor(hl ? p5 : p7, 32);
    U4 L, H;
    L.u[0] = hl ? r0 : p0;
    L.u[1] = hl ? r1 : p1;
    L.u[2] = hl ? p2 : r0;
    L.u[3] = hl ? p3 : r1;
    H.u[0] = hl ? r2 : p4;
    H.u[1] = hl ? r3 : p5;
    H.u[2] = hl ? p6 : r2;
    H.u[3] = hl ? p7 : r3;
    lo = L.h; hi = H.h;
}

#define MFMA(a, b, c) __builtin_amdgcn_mfma_f32_32x32x16_f16((a), (b), (c), 0, 0, 0)

// LDS frag arena: W0c chunks 0..15 @0, W1 chunks @16384, W2 chunks @53248. 62464 B.
__global__ __launch_bounds__(512, 2) void vdc_mlp_kernel(
    const float* __restrict__ feats,      // [N,32]
    const float* __restrict__ dirs,       // [C,N,3]
    const int* __restrict__ sh_deg_p,     // [1]
    const _Float16* __restrict__ ws,
    float* __restrict__ out,              // [C,N,3]
    int N, int C)
{
    __shared__ uint4 arena[3904];         // 62464 B
    char* lds = (char*)arena;

    const int tid   = threadIdx.x;
    const int c     = blockIdx.y;
    const int w     = tid >> 6;           // 0..7
    const int lane  = tid & 63;
    const int ln    = lane & 31;
    const int hl    = lane >> 5;
    const int base0 = blockIdx.x * 512 + w * 64;   // this wave's 64 elements

    // ---- stage frag-linear weights into LDS (single barrier after) ----
    {
        const uint4* srcA = (const uint4*)(ws + (size_t)c * 8192);
        const uint4* srcB = (const uint4*)(ws + (size_t)C * 8192);
        #pragma unroll
        for (int it = 0; it < 8; ++it) {
            int idx = it * 512 + tid;
            if (idx < 3904)
                arena[idx] = (idx < 1024) ? srcA[idx] : srcB[idx - 1024];
        }
    }

    // ---- build layer0 B-frags for 2 element tiles while staging lands ----
    half8 bx0[2], bx1[2], bx2[2], bbias;
    {
        U4 ub;
        ub.u[0] = hl ? 0u : 0x00003C00u;   // f16 1.0 at k-offset 0, hl=0 only
        ub.u[1] = 0u; ub.u[2] = 0u; ub.u[3] = 0u;
        bbias = ub.h;
    }
    int deg = sh_deg_p[0];
    int nbu = (deg + 1) * (deg + 1);
    #pragma unroll
    for (int b = 0; b < 2; ++b) {
        int n = base0 + b * 32 + ln; if (n >= N) n = N - 1;
        const float* fp = feats + (size_t)n * 32 + hl * 8;
        float4 f0 = *(const float4*)(fp);
        float4 f1 = *(const float4*)(fp + 4);
        float4 f2 = *(const float4*)(fp + 16);
        float4 f3 = *(const float4*)(fp + 20);
        U4 u0, u1;
        u0.u[0] = pkr(f0.x, f0.y); u0.u[1] = pkr(f0.z, f0.w);
        u0.u[2] = pkr(f1.x, f1.y); u0.u[3] = pkr(f1.z, f1.w);
        u1.u[0] = pkr(f2.x, f2.y); u1.u[1] = pkr(f2.z, f2.w);
        u1.u[2] = pkr(f3.x, f3.y); u1.u[3] = pkr(f3.z, f3.w);
        bx0[b] = u0.h; bx1[b] = u1.h;

        const float* dp = dirs + ((size_t)c * N + n) * 3;
        float dx = dp[0], dy = dp[1], dz = dp[2];
        float nrm = sqrtf(dx * dx + dy * dy + dz * dz);
        float inv = 1.0f / fmaxf(nrm, 1e-12f);
        float x = dx * inv, y = dy * inv, z = dz * inv;

        float z2     = z * z;
        float fTmp0B = -1.092548430592079f * z;
        float fC1    = x * x - y * y;
        float fS1    = 2.0f * x * y;
        float fTmp0C = -2.285228997322329f * z2 + 0.4570457994644658f;
        float fTmp1B = 1.445305721320277f * z;
        float fC2    = x * fC1 - y * fS1;
        float fS2    = x * fS1 + y * fC1;

        float sh[16];
        sh[0]  = 0.2820947917738781f;
        sh[1]  = -0.48860251190292f * y;
        sh[2]  = 0.48860251190292f * z;
        sh[3]  = -0.48860251190292f * x;
        sh[4]  = 0.5462742152960395f * fS1;
        sh[5]  = fTmp0B * y;
        sh[6]  = 0.9461746957575601f * z2 - 0.3153915652525201f;
        sh[7]  = fTmp0B * x;
        sh[8]  = 0.5462742152960395f * fC1;
        sh[9]  = -0.5900435899266435f * fS2;
        sh[10] = fTmp1B * fS1;
        sh[11] = fTmp0C * y;
        sh[12] = z * (1.865881662950577f * z2 - 1.119528997770346f);
        sh[13] = fTmp0C * x;
        sh[14] = fTmp1B * fC1;
        sh[15] = -0.5900435899266435f * fC2;
        #pragma unroll
        for (int i = 0; i < 16; ++i) if (i >= nbu) sh[i] = 0.0f;

        float s[8];
        #pragma unroll
        for (int i = 0; i < 8; ++i) s[i] = hl ? sh[8 + i] : sh[i];
        U4 u2;
        u2.u[0] = pkr(s[0], s[1]); u2.u[1] = pkr(s[2], s[3]);
        u2.u[2] = pkr(s[4], s[5]); u2.u[3] = pkr(s[6], s[7]);
        bx2[b] = u2.h;
    }

    __syncthreads();

    const char* fr = lds + lane * 16;     // per-lane frag base; chunk offsets are imm

    // ---- layer 0 + transition -> hx ----
    half8 hx[2][8];
    #pragma unroll
    for (int mt = 0; mt < 4; ++mt) {
        half8 a0 = *(const half8*)(fr + (mt * 4 + 0) * 1024);
        half8 a1 = *(const half8*)(fr + (mt * 4 + 1) * 1024);
        half8 a2 = *(const half8*)(fr + (mt * 4 + 2) * 1024);
        half8 a3 = *(const half8*)(fr + (mt * 4 + 3) * 1024);
        #pragma unroll
        for (int b = 0; b < 2; ++b) {
            floatx16 acc;
            #pragma unroll
            for (int r = 0; r < 16; ++r) acc[r] = 0.0f;
            acc = MFMA(a0, bx0[b], acc);
            acc = MFMA(a1, bx1[b], acc);
            acc = MFMA(a2, bx2[b], acc);
            acc = MFMA(a3, bbias, acc);
            transition(acc, hl, hx[b][2 * mt], hx[b][2 * mt + 1]);
        }
    }

    // ---- layer 1 + transition -> gx ----
    half8 gx[2][8];
    #pragma unroll
    for (int mt = 0; mt < 4; ++mt) {
        const char* ap = fr + 16384 + mt * 9 * 1024;
        #pragma unroll
        for (int b = 0; b < 2; ++b) {
            floatx16 acc;
            #pragma unroll
            for (int r = 0; r < 16; ++r) acc[r] = 0.0f;
            #pragma unroll
            for (int ks = 0; ks < 8; ++ks) {
                half8 a = *(const half8*)(ap + ks * 1024);
                acc = MFMA(a, hx[b][ks], acc);
            }
            half8 ab = *(const half8*)(ap + 8 * 1024);
            acc = MFMA(ab, bbias, acc);
            transition(acc, hl, gx[b][2 * mt], gx[b][2 * mt + 1]);
        }
    }

    // ---- layer 2: rows >=3 garbage, never stored ----
    #pragma unroll
    for (int b = 0; b < 2; ++b) {
        floatx16 acc;
        #pragma unroll
        for (int r = 0; r < 16; ++r) acc[r] = 0.0f;
        const char* ap = fr + 53248;
        #pragma unroll
        for (int ks = 0; ks < 8; ++ks) {
            half8 a = *(const half8*)(ap + ks * 1024);
            acc = MFMA(a, gx[b][ks], acc);
        }
        half8 ab = *(const half8*)(ap + 8 * 1024);
        acc = MFMA(ab, bbias, acc);

        if (hl == 0) {
            int nn = base0 + b * 32 + ln;
            if (nn < N) {
                float* op = out + ((size_t)c * N + nn) * 3;
                op[0] = acc[0];
                op[1] = acc[1];
                op[2] = acc[2];
            }
        }
    }
}

extern "C" void kernel_launch(void* const* d_in, const int* in_sizes, int n_in,
                              void* d_out, int out_size, void* d_ws, size_t ws_size,
                              hipStream_t stream) {
    const float* feats   = (const float*)d_in[0];
    const float* dirs    = (const float*)d_in[1];
    const float* emb_tab = (const float*)d_in[2];
    const float* W0      = (const float*)d_in[3];
    const float* b0      = (const float*)d_in[4];
    const float* W1      = (const float*)d_in[5];
    const float* b1      = (const float*)d_in[6];
    const float* W2      = (const float*)d_in[7];
    const float* b2      = (const float*)d_in[8];
    const int*   eids    = (const int*)d_in[9];
    const int*   shd     = (const int*)d_in[10];
    float* outp          = (float*)d_out;

    int N = in_sizes[0] / 32;    // features [N,32]
    int C = in_sizes[9];         // embed_ids [C]

    _Float16* wsh = (_Float16*)d_ws;

    int ws_elems = C * 8192 + 23040;
    vdc_prep_kernel<<<(ws_elems + 255) / 256, 256, 0, stream>>>(
        W0, W1, W2, b0, b1, b2, emb_tab, eids, C, wsh);

    dim3 grid((N + 511) / 512, C);
    vdc_mlp_kernel<<<grid, 512, 0, stream>>>(
        feats, dirs, shd, wsh, outp, N, C);
}